// Round 13
// baseline (132.320 us; speedup 1.0000x reference)
//
#include <hip/hip_runtime.h>
#include <hip/hip_bf16.h>

#define DIM 1024
#define NHEADS 16
#define HD 64
#define BB 2
#define SS 2048
#define MTOT (BB*SS)      // 4096
#define SCALE 0.125f      // HD^-0.5
#define QSCALE 0.1803368801111204f   // SCALE * log2(e): scores land in exp2 domain

typedef __attribute__((ext_vector_type(8))) short bf16x8;   // 8 bf16 = 4 VGPRs
typedef __attribute__((ext_vector_type(4))) float f32x4;

__device__ __forceinline__ float bf2f(short u) {
  union { float f; unsigned int i; } v;
  v.i = ((unsigned int)(unsigned short)u) << 16;
  return v.f;
}
__device__ __forceinline__ short f2bf(float f) {
  union { float f; unsigned int i; } v; v.f = f;
  unsigned int r = v.i + 0x7fffu + ((v.i >> 16) & 1u);   // RNE
  return (short)(r >> 16);
}
__device__ __forceinline__ unsigned int cvtpk_bf16(float lo, float hi) {
  unsigned int r;
  asm("v_cvt_pk_bf16_f32 %0, %1, %2" : "=v"(r) : "v"(lo), "v"(hi));
  return r;
}
// async global->LDS, 16B per lane; LDS dest = WAVE-UNIFORM base, HW adds lane*16 (m97/m104)
__device__ __forceinline__ void async_load16(const short* g, short* l) {
  __builtin_amdgcn_global_load_lds(
      (const __attribute__((address_space(1))) unsigned int*)g,
      (__attribute__((address_space(3))) unsigned int*)l, 16, 0, 0);
}

// ---------------- fused fp32->bf16 (x, w_qkv, w_out) + RoPE table, one launch ----------------
__global__ void cvt3_kernel(const float* __restrict__ a, short* __restrict__ oa, int na,
                            const float* __restrict__ b, short* __restrict__ ob, int nb,
                            const float* __restrict__ c, short* __restrict__ oc, int nc,
                            float* __restrict__ ct, float* __restrict__ st) {
  int gid = blockIdx.x * blockDim.x + threadIdx.x;
  if (gid < SS * 32) {                 // RoPE cos/sin table
    int s = gid >> 5, j = gid & 31;
    float inv = 1.0f / powf(10000.0f, (float)(2 * j) / 64.0f);
    float ang = (float)s * inv;
    ct[gid] = cosf(ang);
    st[gid] = sinf(ang);
  }
  int stride = gridDim.x * blockDim.x;
  int tot = na + nb + nc;              // quad counts
  for (int q = gid; q < tot; q += stride) {
    const float* src; short* dst; int off;
    if (q < na)            { src = a; dst = oa; off = q; }
    else if (q < na + nb)  { src = b; dst = ob; off = q - na; }
    else                   { src = c; dst = oc; off = q - na - nb; }
    float4 v = *(const float4*)(src + (size_t)off * 4);
    short4 o;
    o.x = f2bf(v.x); o.y = f2bf(v.y); o.z = f2bf(v.z); o.w = f2bf(v.w);
    *(short4*)(dst + (size_t)off * 4) = o;
  }
}

// ---------------- GEMM: C[m][n] = sum_k A[m][k] * B[n][k]  (both row-major, K-contig) ----------------
// 128xBN tile, 4 waves (2x2), BK=32, global_load_lds width=16 into linear LDS.
template<int BN, bool OUT_F32>
__global__ __launch_bounds__(256) void gemm_bt(
    const short* __restrict__ A, const short* __restrict__ B,
    void* __restrict__ C, int M, int N, int K) {
  constexpr int NFR = BN / 32;         // per-wave 16-col frags
  __shared__ __align__(16) short As[128][32];
  __shared__ __align__(16) short Bs[BN][32];
  const int nbx = N / BN;
  const int chunk = gridDim.x >> 3;
  const int wg = (blockIdx.x & 7) * chunk + (blockIdx.x >> 3);
  const int m0 = (wg / nbx) * 128, n0 = (wg % nbx) * BN;
  const int tid = threadIdx.x;
  const int lane = tid & 63;
  const int wid = tid >> 6;
  const int wm = (wid >> 1) * 64, wn = (wid & 1) * (BN / 2);
  const int row = lane & 15, kg = (lane >> 4) * 8;
  const int lrow = lane >> 2;          // 0..15 within a 16-row chunk
  const int lcol = (lane & 3) * 8;     // 0,8,16,24 shorts

  f32x4 acc[4][NFR];
#pragma unroll
  for (int m = 0; m < 4; m++)
#pragma unroll
    for (int n = 0; n < NFR; n++) acc[m][n] = (f32x4){0.f, 0.f, 0.f, 0.f};

  for (int kk = 0; kk < K; kk += 32) {
    __syncthreads();                   // previous tile fully consumed
#pragma unroll
    for (int i = 0; i < 2; i++) {
      int base = i * 64 + wid * 16;    // 16-row chunk staged by this wave
      async_load16(A + (size_t)(m0 + base + lrow) * K + kk + lcol, &As[base][0]);
    }
    if constexpr (BN == 128) {
#pragma unroll
      for (int i = 0; i < 2; i++) {
        int base = i * 64 + wid * 16;
        async_load16(B + (size_t)(n0 + base + lrow) * K + kk + lcol, &Bs[base][0]);
      }
    } else {
      int base = wid * 16;
      async_load16(B + (size_t)(n0 + base + lrow) * K + kk + lcol, &Bs[base][0]);
    }
    __syncthreads();                   // vmcnt drained -> tiles ready
    bf16x8 af[4], bfr[NFR];
#pragma unroll
    for (int m = 0; m < 4; m++) af[m] = *(const bf16x8*)(&As[wm + m * 16 + row][kg]);
#pragma unroll
    for (int n = 0; n < NFR; n++) bfr[n] = *(const bf16x8*)(&Bs[wn + n * 16 + row][kg]);
#pragma unroll
    for (int m = 0; m < 4; m++)
#pragma unroll
      for (int n = 0; n < NFR; n++)
        acc[m][n] = __builtin_amdgcn_mfma_f32_16x16x32_bf16(af[m], bfr[n], acc[m][n], 0, 0, 0);
  }
  const int orow = (lane >> 4) * 4, ocol = lane & 15;
#pragma unroll
  for (int m = 0; m < 4; m++)
#pragma unroll
    for (int n = 0; n < NFR; n++)
#pragma unroll
      for (int r = 0; r < 4; r++) {
        int gr = m0 + wm + m * 16 + orow + r;
        int gc = n0 + wn + n * 16 + ocol;
        if (OUT_F32) ((float*)C)[(size_t)gr * N + gc] = acc[m][n][r];
        else         ((short*)C)[(size_t)gr * N + gc] = f2bf(acc[m][n][r]);
      }
}

// ---------------- fused RoPE(Q,K) + V transpose/permute, one launch ----------------
// K and Vt stored PRE-SWIZZLED in global (rule #21): within each 128B row, 16B chunk j
// lives at physical chunk j ^ (row&7). attn stages linearly via global_load_lds and
// XORs frag reads -> conflict-free (measured 0 conflicts, r9/r10/r12).
__global__ __launch_bounds__(256) void ropev_kernel(
    const short* __restrict__ qkv, const float* __restrict__ ct, const float* __restrict__ st,
    short* __restrict__ Q, short* __restrict__ K, short* __restrict__ Vt) {
  int bh = blockIdx.y;
  int b = bh >> 4, h = bh & 15;
  int t = threadIdx.x;
  if (blockIdx.x < SS / 64) {
    int s0 = blockIdx.x * 64;
    int rl = t >> 2;
    int d8 = (t & 3) * 8;
    int s = s0 + rl;
    size_t inbase = ((size_t)(b * SS + s)) * 3072 + h * 64 + d8;
    size_t outbase = ((size_t)bh * SS + s) * 64;
    float c[8], sn[8];
#pragma unroll
    for (int j = 0; j < 8; j++) { c[j] = ct[s * 32 + d8 + j]; sn[j] = st[s * 32 + d8 + j]; }
    {
      bf16x8 x1 = *(const bf16x8*)(qkv + inbase);
      bf16x8 x2 = *(const bf16x8*)(qkv + inbase + 32);
      bf16x8 o1, o2;
#pragma unroll
      for (int j = 0; j < 8; j++) {
        float a = bf2f(x1[j]), bb = bf2f(x2[j]);
        o1[j] = f2bf((a * c[j] - bb * sn[j]) * QSCALE);
        o2[j] = f2bf((bb * c[j] + a * sn[j]) * QSCALE);
      }
      *(bf16x8*)(Q + outbase + d8) = o1;        // Q not swizzled
      *(bf16x8*)(Q + outbase + d8 + 32) = o2;
    }
    {
      bf16x8 x1 = *(const bf16x8*)(qkv + inbase + 1024);
      bf16x8 x2 = *(const bf16x8*)(qkv + inbase + 1024 + 32);
      bf16x8 o1, o2;
#pragma unroll
      for (int j = 0; j < 8; j++) {
        float a = bf2f(x1[j]), bb = bf2f(x2[j]);
        o1[j] = f2bf(a * c[j] - bb * sn[j]);
        o2[j] = f2bf(bb * c[j] + a * sn[j]);
      }
      int pc = (t & 3) ^ (s & 7);               // physical chunk for logical chunk t&3
      *(bf16x8*)(K + outbase + pc * 8) = o1;
      *(bf16x8*)(K + outbase + (pc ^ 4) * 8) = o2;   // logical chunk +4
    }
  } else {
    __shared__ short ls[64][72];
    int s0 = (blockIdx.x - SS / 64) * 64;
#pragma unroll
    for (int p = 0; p < 2; p++) {
      int idx = p * 256 + t;
      int r = idx >> 3, c8 = (idx & 7) * 8;
      *(bf16x8*)(&ls[r][c8]) =
          *(const bf16x8*)(qkv + ((size_t)(b * SS + s0 + r)) * 3072 + 2048 + h * 64 + c8);
    }
    __syncthreads();
    int dl = t >> 2, sg = (t & 3) * 16;
    int c = sg >> 5, hi = (sg >> 4) & 1;
    short tmp[16];
#pragma unroll
    for (int j = 0; j < 16; j++) tmp[j] = ls[sg + j][dl];
    size_t rowbase = ((size_t)bh * 64 + dl) * SS + s0;
#pragma unroll
    for (int g = 0; g < 4; g++) {
      short4 o = { tmp[4 * g], tmp[4 * g + 1], tmp[4 * g + 2], tmp[4 * g + 3] };
      int pc = (c * 4 + g) ^ (dl & 7);          // slot-permuted logical chunk c*4+g, swizzled
      *(short4*)(Vt + rowbase + pc * 8 + hi * 4) = o;
    }
  }
}

// ---------------- Flash attention, causal. Q128 blocks: 32 q-rows PER WAVE (2 frags) ----------
// r12 diagnosis: VALU 51% + LDS-pipe ~50%, both half-busy -> latency-bound. Each K/V frag
// read served only 16 q. Now each wave owns TWO 16-row q-frags: K/V LDS reads and staging
// are SHARED across frags (halved per unit work), softmax chains ×2 = double ILP.
// Split-KV: heavy tile qtH=15-pr has 2qtH+2 kv-tiles; half0 = tiles [0,17) (partial),
// half1 = tiles [17,nH) (partial) + light tile pr complete (final). 17 vs 17 balanced.
// Generic per-frag masking: skip n-block if above frag q-range; elementwise near diagonal.
__global__ __launch_bounds__(256) void attn_kernel(
    const short* __restrict__ Qp, const short* __restrict__ Kp, const short* __restrict__ Vt,
    short* __restrict__ O, float* __restrict__ Pf) {
  __shared__ __align__(16) short KsF[2][64 * 64];   // [buf][kv][d-chunks swizzled]
  __shared__ __align__(16) short VsF[2][64 * 64];   // [buf][d][kv-slot chunks swizzled]
  int flat = blockIdx.x;
  int wk = (flat & 7) * 64 + (flat >> 3);    // 512 blocks: 4 bh per XCD, bijective
  int bh = wk >> 4;
  int sub = wk & 15;
  int pr = sub >> 1, half = sub & 1;
  int b = bh >> 4, h = bh & 15;
  int tid = threadIdx.x, lane = tid & 63, w = tid >> 6;
  int row = lane & 15, grp = lane >> 4;
  const int qtH = 15 - pr;
  const int nH = 2 * qtH + 2;                // kv tiles needed by heavy q-tile
  const int nseg = 1 + half;
  const int ck = (grp ^ (row & 7)) * 8;      // swizzled chunk offset (shorts)
  const short one_bf = (short)0x3F80;        // bf16 1.0
  const bf16x8 ones = {one_bf, one_bf, one_bf, one_bf, one_bf, one_bf, one_bf, one_bf};

  const short* Kbase = Kp + (size_t)bh * SS * 64;
  const short* Vbase = Vt + (size_t)bh * 64 * SS;
  const int sr8 = lane >> 3;
  const int sc8 = (lane & 7) * 8;

  auto STAGE = [&](int bufi, int kv0) {      // 4 gload_lds per wave
#pragma unroll
    for (int i = 0; i < 2; i++) {
      int rbase = i * 32 + w * 8;
      async_load16(Kbase + (size_t)(kv0 + rbase + sr8) * 64 + sc8, &KsF[bufi][rbase * 64]);
      async_load16(Vbase + (size_t)(rbase + sr8) * SS + kv0 + sc8, &VsF[bufi][rbase * 64]);
    }
  };

  int cur = 0;
  STAGE(0, (half ? 17 : 0) * 64);

#pragma unroll 1
  for (int s = 0; s < nseg; s++) {
    const int qt  = s ? pr : qtH;
    const int kts = s ? 0 : (half ? 17 : 0);
    const int kte = s ? (2 * pr + 1) : (half ? nH - 1 : 16);
    const bool fin = (s == 1);
    const int q0 = qt * 128;
    const int qa = q0 + w * 16 + row;        // frag0 q; frag1 = qa + 64
    bf16x8 qf[2][2];
#pragma unroll
    for (int f = 0; f < 2; f++) {
      size_t qb_ = ((size_t)bh * SS + qa + f * 64) * 64 + grp * 8;
      qf[f][0] = *(const bf16x8*)(Qp + qb_);
      qf[f][1] = *(const bf16x8*)(Qp + qb_ + 32);
    }
    f32x4 acc[2][4];
    f32x4 acc2[2];
    float m[2] = {-1e30f, -1e30f};
#pragma unroll
    for (int f = 0; f < 2; f++) {
      acc2[f] = (f32x4){0.f, 0.f, 0.f, 0.f};
#pragma unroll
      for (int d = 0; d < 4; d++) acc[f][d] = (f32x4){0.f, 0.f, 0.f, 0.f};
    }

#pragma unroll 1
    for (int kt = kts; kt <= kte; kt++) {
      int kv0 = kt * 64;
      bool more = (kt < kte) || (s + 1 < nseg);   // wave-uniform
      if (more) {
        STAGE(cur ^ 1, kt < kte ? kv0 + 64 : 0);
        asm volatile("s_waitcnt vmcnt(4)" ::: "memory");
      } else {
        asm volatile("s_waitcnt vmcnt(0)" ::: "memory");
      }
      __builtin_amdgcn_sched_barrier(0);
      __builtin_amdgcn_s_barrier();
      __builtin_amdgcn_sched_barrier(0);
      const short* Kc = &KsF[cur][0];
      const short* Vc = &VsF[cur][0];

      // QK^T: K-frag reads SHARED across the 2 q-frags
      float sv[2][4][4];
      __builtin_amdgcn_s_setprio(1);
#pragma unroll
      for (int n = 0; n < 4; n++) {
        int kvn = kv0 + n * 16;
        const short* kr_ = Kc + (n * 16 + row) * 64;
        bf16x8 kf0 = *(const bf16x8*)(kr_ + ck);
        bf16x8 kf1 = *(const bf16x8*)(kr_ + (ck ^ 32));
#pragma unroll
        for (int f = 0; f < 2; f++) {
          if (kvn > q0 + f * 64 + w * 16 + 15) {     // block fully above this frag
#pragma unroll
            for (int r = 0; r < 4; r++) sv[f][n][r] = -1e30f;
            continue;
          }
          f32x4 sf = (f32x4){0.f, 0.f, 0.f, 0.f};
          sf = __builtin_amdgcn_mfma_f32_16x16x32_bf16(kf0, qf[f][0], sf, 0, 0, 0);
          sf = __builtin_amdgcn_mfma_f32_16x16x32_bf16(kf1, qf[f][1], sf, 0, 0, 0);
#pragma unroll
          for (int r = 0; r < 4; r++) sv[f][n][r] = sf[r];
        }
      }
      __builtin_amdgcn_s_setprio(0);
      // elementwise causal mask only where a block touches the diagonal of a frag
#pragma unroll
      for (int f = 0; f < 2; f++) {
        int blo = q0 + f * 64 + w * 16;
        int qfl = qa + f * 64;
#pragma unroll
        for (int n = 0; n < 4; n++) {
          int kvn = kv0 + n * 16;
          if (kvn <= blo + 15 && kvn + 15 > blo) {
#pragma unroll
            for (int r = 0; r < 4; r++) {
              int kv = kvn + grp * 4 + r;
              if (kv > qfl) sv[f][n][r] = -1e30f;
            }
          }
        }
      }
      // softmax per frag (independent chains = ILP)
#pragma unroll
      for (int f = 0; f < 2; f++) {
        float t0 = fmaxf(fmaxf(sv[f][0][0], sv[f][0][1]), sv[f][0][2]);
        float t1 = fmaxf(fmaxf(sv[f][0][3], sv[f][1][0]), sv[f][1][1]);
        float t2 = fmaxf(fmaxf(sv[f][1][2], sv[f][1][3]), sv[f][2][0]);
        float t3 = fmaxf(fmaxf(sv[f][2][1], sv[f][2][2]), sv[f][2][3]);
        float t4 = fmaxf(fmaxf(sv[f][3][0], sv[f][3][1]), sv[f][3][2]);
        float pmax = fmaxf(fmaxf(fmaxf(t0, t1), fmaxf(t2, t3)), fmaxf(t4, sv[f][3][3]));
        pmax = fmaxf(pmax, __shfl_xor(pmax, 16));
        pmax = fmaxf(pmax, __shfl_xor(pmax, 32));
        if (__any(pmax - m[f] > 8.f)) {            // T13 defer-rescale
          float mnew = fmaxf(m[f], pmax);
          float resc = __builtin_amdgcn_exp2f(m[f] - mnew);
          m[f] = mnew;
#pragma unroll
          for (int d = 0; d < 4; d++)
#pragma unroll
            for (int r = 0; r < 4; r++) acc[f][d][r] *= resc;
#pragma unroll
          for (int r = 0; r < 4; r++) acc2[f][r] *= resc;
        }
#pragma unroll
        for (int n = 0; n < 4; n++)
#pragma unroll
          for (int r = 0; r < 4; r++)
            sv[f][n][r] = __builtin_amdgcn_exp2f(sv[f][n][r] - m[f]);
      }
      // PV + l: V-frag reads SHARED across frags; slot j -> kv = c*32+16*(j>>2)+grp*4+(j&3)
      __builtin_amdgcn_s_setprio(1);
#pragma unroll
      for (int c = 0; c < 2; c++) {
        union { unsigned int u[4]; bf16x8 v; } pu0, pu1;
        pu0.u[0] = cvtpk_bf16(sv[0][2 * c][0], sv[0][2 * c][1]);
        pu0.u[1] = cvtpk_bf16(sv[0][2 * c][2], sv[0][2 * c][3]);
        pu0.u[2] = cvtpk_bf16(sv[0][2 * c + 1][0], sv[0][2 * c + 1][1]);
        pu0.u[3] = cvtpk_bf16(sv[0][2 * c + 1][2], sv[0][2 * c + 1][3]);
        pu1.u[0] = cvtpk_bf16(sv[1][2 * c][0], sv[1][2 * c][1]);
        pu1.u[1] = cvtpk_bf16(sv[1][2 * c][2], sv[1][2 * c][3]);
        pu1.u[2] = cvtpk_bf16(sv[1][2 * c + 1][0], sv[1][2 * c + 1][1]);
        pu1.u[3] = cvtpk_bf16(sv[1][2 * c + 1][2], sv[1][2 * c + 1][3]);
#pragma unroll
        for (int dm = 0; dm < 4; dm++) {
          const short* vr_ = Vc + (dm * 16 + row) * 64;
          bf16x8 vf = *(const bf16x8*)(vr_ + (ck ^ (c * 32)));
          acc[0][dm] = __builtin_amdgcn_mfma_f32_16x16x32_bf16(vf, pu0.v, acc[0][dm], 0, 0, 0);
          acc[1][dm] = __builtin_amdgcn_mfma_f32_16x16x32_bf16(vf, pu1.v, acc[1][dm], 0, 0, 0);
        }
        acc2[0] = __builtin_amdgcn_mfma_f32_16x16x32_bf16(ones, pu0.v, acc2[0], 0, 0, 0);
        acc2[1] = __builtin_amdgcn_mfma_f32_16x16x32_bf16(ones, pu1.v, acc2[1], 0, 0, 0);
      }
      __builtin_amdgcn_s_setprio(0);
      __builtin_amdgcn_sched_barrier(0);
      __builtin_amdgcn_s_barrier();
      __builtin_amdgcn_sched_barrier(0);
      cur ^= 1;
    }
    if (fin) {
#pragma unroll
      for (int f = 0; f < 2; f++) {
        float linv = 1.0f / acc2[f][0];
        size_t ob = ((size_t)(b * SS + qa + f * 64)) * 1024 + h * 64 + grp * 4;
#pragma unroll
        for (int dm = 0; dm < 4; dm++) {
          union { unsigned int u[2]; short4 s4; } ou;
          ou.u[0] = cvtpk_bf16(acc[f][dm][0] * linv, acc[f][dm][1] * linv);
          ou.u[1] = cvtpk_bf16(acc[f][dm][2] * linv, acc[f][dm][3] * linv);
          *(short4*)(O + ob + dm * 16) = ou.s4;
        }
      }
    } else {
      // partial: [slot][128 q][68]: acc at 0..63, m at 64, l at 65
      int slot = (bh * 8 + (qtH - 8)) * 2 + half;
#pragma unroll
      for (int f = 0; f < 2; f++) {
        float* P = Pf + (size_t)slot * 128 * 68 + (f * 64 + w * 16 + row) * 68;
#pragma unroll
        for (int dm = 0; dm < 4; dm++) {
          f32x4 a = acc[f][dm];
          *(float4*)(P + dm * 16 + grp * 4) = *(float4*)&a;
        }
        if (grp == 0) { P[64] = m[f]; P[65] = acc2[f][0]; }
      }
    }
  }
}

// ---------------- merge the two heavy-half partials (128-q tiles) ----------------
__global__ __launch_bounds__(128) void merge_kernel(const float* __restrict__ Pf, short* __restrict__ O) {
  int g = blockIdx.x;                  // 0..255 = bh*8 + (qtH-8)
  int bh = g >> 3, ht = g & 7;
  int b = bh >> 4, h = bh & 15;
  int qt = ht + 8;
  int t = threadIdx.x;                 // q within 128-row tile
  const float* p0 = Pf + ((size_t)(g * 2)) * 128 * 68 + t * 68;
  const float* p1 = p0 + 128 * 68;
  float m0 = p0[64], l0 = p0[65], m1 = p1[64], l1 = p1[65];
  float mM = fmaxf(m0, m1);
  float e0 = __builtin_amdgcn_exp2f(m0 - mM);
  float e1 = __builtin_amdgcn_exp2f(m1 - mM);
  float linv = 1.0f / (e0 * l0 + e1 * l1);
  size_t ob = ((size_t)(b * SS + qt * 128 + t)) * 1024 + h * 64;
#pragma unroll
  for (int d8 = 0; d8 < 8; d8++) {
    float4 a0 = *(const float4*)(p0 + d8 * 8);
    float4 a1 = *(const float4*)(p1 + d8 * 8);
    float4 b0 = *(const float4*)(p0 + d8 * 8 + 4);
    float4 b1 = *(const float4*)(p1 + d8 * 8 + 4);
    union { unsigned int u[4]; short4 s4[2]; } ou;
    ou.u[0] = cvtpk_bf16((e0 * a0.x + e1 * a1.x) * linv, (e0 * a0.y + e1 * a1.y) * linv);
    ou.u[1] = cvtpk_bf16((e0 * a0.z + e1 * a1.z) * linv, (e0 * a0.w + e1 * a1.w) * linv);
    ou.u[2] = cvtpk_bf16((e0 * b0.x + e1 * b1.x) * linv, (e0 * b0.y + e1 * b1.y) * linv);
    ou.u[3] = cvtpk_bf16((e0 * b0.z + e1 * b1.z) * linv, (e0 * b0.w + e1 * b1.w) * linv);
    *(short4*)(O + ob + d8 * 8) = ou.s4[0];
    *(short4*)(O + ob + d8 * 8 + 4) = ou.s4[1];
  }
}

extern "C" void kernel_launch(void* const* d_in, const int* in_sizes, int n_in,
                              void* d_out, int out_size, void* d_ws, size_t ws_size,
                              hipStream_t stream) {
  (void)in_sizes; (void)n_in; (void)out_size; (void)ws_size;
  const float* x     = (const float*)d_in[0];
  const float* w_qkv = (const float*)d_in[1];
  const float* w_out = (const float*)d_in[2];
  float* out = (float*)d_out;

  char* ws = (char*)d_ws;
  size_t off = 0;
  auto alloc = [&](size_t bytes) -> void* {
    void* p = ws + off;
    off += (bytes + 255) & ~(size_t)255;
    return p;
  };
  short* xb    = (short*)alloc((size_t)MTOT * DIM * 2);      // dead after GEMM1
  short* wqkvb = (short*)alloc((size_t)3072 * 1024 * 2);
  short* woutb = (short*)alloc((size_t)1024 * 1024 * 2);
  short* qkvb  = (short*)alloc((size_t)MTOT * 3072 * 2);     // dead after ropev -> partial scratch
  short* Qb    = (short*)alloc((size_t)32 * SS * 64 * 2);
  short* Kb    = (short*)alloc((size_t)32 * SS * 64 * 2);
  short* Vtb   = (short*)alloc((size_t)32 * 64 * SS * 2);
  float* ct    = (float*)alloc((size_t)SS * 32 * 4);
  float* st    = (float*)alloc((size_t)SS * 32 * 4);
  short* attnb = xb;         // reuse: xb's last read is GEMM1 (stream-ordered)
  float* Pf    = (float*)qkvb;  // partial scratch: 512 slots * 128 * 68 * 4B = 17.8MB <= 25.2MB

  cvt3_kernel<<<2048, 256, 0, stream>>>(x, xb, MTOT * DIM / 4,
                                        w_qkv, wqkvb, 3072 * 1024 / 4,
                                        w_out, woutb, 1024 * 1024 / 4, ct, st);
  gemm_bt<128, false><<<(3072 / 128) * (MTOT / 128), 256, 0, stream>>>(xb, wqkvb, qkvb, MTOT, 3072, 1024);
  ropev_kernel<<<dim3(2 * SS / 64, 32), 256, 0, stream>>>(qkvb, ct, st, Qb, Kb, Vtb);
  attn_kernel<<<512, 256, 0, stream>>>(Qb, Kb, Vtb, attnb, Pf);
  merge_kernel<<<256, 128, 0, stream>>>(Pf, attnb);
  gemm_bt<64, true><<<(1024 / 64) * (MTOT / 128), 256, 0, stream>>>(attnb, woutb, out, MTOT, 1024, 1024);
}

// Round 15
// 127.984 us; speedup vs baseline: 1.0339x; 1.0339x over previous
//
#include <hip/hip_runtime.h>
#include <hip/hip_bf16.h>

#define DIM 1024
#define NHEADS 16
#define HD 64
#define BB 2
#define SS 2048
#define MTOT (BB*SS)      // 4096
#define SCALE 0.125f      // HD^-0.5
#define QSCALE 0.1803368801111204f   // SCALE * log2(e): scores land in exp2 domain

typedef __attribute__((ext_vector_type(8))) short bf16x8;   // 8 bf16 = 4 VGPRs
typedef __attribute__((ext_vector_type(4))) float f32x4;

__device__ __forceinline__ float bf2f(short u) {
  union { float f; unsigned int i; } v;
  v.i = ((unsigned int)(unsigned short)u) << 16;
  return v.f;
}
__device__ __forceinline__ short f2bf(float f) {
  union { float f; unsigned int i; } v; v.f = f;
  unsigned int r = v.i + 0x7fffu + ((v.i >> 16) & 1u);   // RNE
  return (short)(r >> 16);
}
__device__ __forceinline__ unsigned int cvtpk_bf16(float lo, float hi) {
  unsigned int r;
  asm("v_cvt_pk_bf16_f32 %0, %1, %2" : "=v"(r) : "v"(lo), "v"(hi));
  return r;
}
// async global->LDS, 16B per lane; LDS dest = WAVE-UNIFORM base, HW adds lane*16 (m97/m104)
__device__ __forceinline__ void async_load16(const short* g, short* l) {
  __builtin_amdgcn_global_load_lds(
      (const __attribute__((address_space(1))) unsigned int*)g,
      (__attribute__((address_space(3))) unsigned int*)l, 16, 0, 0);
}

// ---------------- fused fp32->bf16 (x, w_qkv, w_out) + RoPE table, one launch ----------------
__global__ void cvt3_kernel(const float* __restrict__ a, short* __restrict__ oa, int na,
                            const float* __restrict__ b, short* __restrict__ ob, int nb,
                            const float* __restrict__ c, short* __restrict__ oc, int nc,
                            float* __restrict__ ct, float* __restrict__ st) {
  int gid = blockIdx.x * blockDim.x + threadIdx.x;
  if (gid < SS * 32) {                 // RoPE cos/sin table
    int s = gid >> 5, j = gid & 31;
    float inv = 1.0f / powf(10000.0f, (float)(2 * j) / 64.0f);
    float ang = (float)s * inv;
    ct[gid] = cosf(ang);
    st[gid] = sinf(ang);
  }
  int stride = gridDim.x * blockDim.x;
  int tot = na + nb + nc;              // quad counts
  for (int q = gid; q < tot; q += stride) {
    const float* src; short* dst; int off;
    if (q < na)            { src = a; dst = oa; off = q; }
    else if (q < na + nb)  { src = b; dst = ob; off = q - na; }
    else                   { src = c; dst = oc; off = q - na - nb; }
    float4 v = *(const float4*)(src + (size_t)off * 4);
    short4 o;
    o.x = f2bf(v.x); o.y = f2bf(v.y); o.z = f2bf(v.z); o.w = f2bf(v.w);
    *(short4*)(dst + (size_t)off * 4) = o;
  }
}

// ---------------- GEMM: C[m][n] = sum_k A[m][k] * B[n][k]  (both row-major, K-contig) ----------------
// 128xBN tile, 4 waves (2x2), BK=32, global_load_lds width=16 into linear LDS.
// BN=128 for GEMM1 (grid 768 = 3/CU); BN=64 for GEMM2 (grid 512 = 2/CU).
// Direct-store epilogue (LDS-epilogue and fused-transform epilogues both regressed — r7, r11).
template<int BN, bool OUT_F32>
__global__ __launch_bounds__(256) void gemm_bt(
    const short* __restrict__ A, const short* __restrict__ B,
    void* __restrict__ C, int M, int N, int K) {
  constexpr int NFR = BN / 32;         // per-wave 16-col frags
  __shared__ __align__(16) short As[128][32];
  __shared__ __align__(16) short Bs[BN][32];
  const int nbx = N / BN;
  const int chunk = gridDim.x >> 3;
  const int wg = (blockIdx.x & 7) * chunk + (blockIdx.x >> 3);
  const int m0 = (wg / nbx) * 128, n0 = (wg % nbx) * BN;
  const int tid = threadIdx.x;
  const int lane = tid & 63;
  const int wid = tid >> 6;
  const int wm = (wid >> 1) * 64, wn = (wid & 1) * (BN / 2);
  const int row = lane & 15, kg = (lane >> 4) * 8;
  const int lrow = lane >> 2;          // 0..15 within a 16-row chunk
  const int lcol = (lane & 3) * 8;     // 0,8,16,24 shorts

  f32x4 acc[4][NFR];
#pragma unroll
  for (int m = 0; m < 4; m++)
#pragma unroll
    for (int n = 0; n < NFR; n++) acc[m][n] = (f32x4){0.f, 0.f, 0.f, 0.f};

  for (int kk = 0; kk < K; kk += 32) {
    __syncthreads();                   // previous tile fully consumed
#pragma unroll
    for (int i = 0; i < 2; i++) {
      int base = i * 64 + wid * 16;    // 16-row chunk staged by this wave
      async_load16(A + (size_t)(m0 + base + lrow) * K + kk + lcol, &As[base][0]);
    }
    if constexpr (BN == 128) {
#pragma unroll
      for (int i = 0; i < 2; i++) {
        int base = i * 64 + wid * 16;
        async_load16(B + (size_t)(n0 + base + lrow) * K + kk + lcol, &Bs[base][0]);
      }
    } else {
      int base = wid * 16;
      async_load16(B + (size_t)(n0 + base + lrow) * K + kk + lcol, &Bs[base][0]);
    }
    __syncthreads();                   // vmcnt drained -> tiles ready
    bf16x8 af[4], bfr[NFR];
#pragma unroll
    for (int m = 0; m < 4; m++) af[m] = *(const bf16x8*)(&As[wm + m * 16 + row][kg]);
#pragma unroll
    for (int n = 0; n < NFR; n++) bfr[n] = *(const bf16x8*)(&Bs[wn + n * 16 + row][kg]);
#pragma unroll
    for (int m = 0; m < 4; m++)
#pragma unroll
      for (int n = 0; n < NFR; n++)
        acc[m][n] = __builtin_amdgcn_mfma_f32_16x16x32_bf16(af[m], bfr[n], acc[m][n], 0, 0, 0);
  }
  const int orow = (lane >> 4) * 4, ocol = lane & 15;
#pragma unroll
  for (int m = 0; m < 4; m++)
#pragma unroll
    for (int n = 0; n < NFR; n++)
#pragma unroll
      for (int r = 0; r < 4; r++) {
        int gr = m0 + wm + m * 16 + orow + r;
        int gc = n0 + wn + n * 16 + ocol;
        if (OUT_F32) ((float*)C)[(size_t)gr * N + gc] = acc[m][n][r];
        else         ((short*)C)[(size_t)gr * N + gc] = f2bf(acc[m][n][r]);
      }
}

// ---------------- fused RoPE(Q,K) + V transpose/permute, one launch ----------------
// K and Vt stored PRE-SWIZZLED in global (rule #21): within each 128B row, 16B chunk j
// lives at physical chunk j ^ (row&7). attn stages linearly via global_load_lds and
// XORs frag reads -> conflict-free (measured 0 conflicts, r9/r10/r12).
__global__ __launch_bounds__(256) void ropev_kernel(
    const short* __restrict__ qkv, const float* __restrict__ ct, const float* __restrict__ st,
    short* __restrict__ Q, short* __restrict__ K, short* __restrict__ Vt) {
  int bh = blockIdx.y;
  int b = bh >> 4, h = bh & 15;
  int t = threadIdx.x;
  if (blockIdx.x < SS / 64) {
    int s0 = blockIdx.x * 64;
    int rl = t >> 2;
    int d8 = (t & 3) * 8;
    int s = s0 + rl;
    size_t inbase = ((size_t)(b * SS + s)) * 3072 + h * 64 + d8;
    size_t outbase = ((size_t)bh * SS + s) * 64;
    float c[8], sn[8];
#pragma unroll
    for (int j = 0; j < 8; j++) { c[j] = ct[s * 32 + d8 + j]; sn[j] = st[s * 32 + d8 + j]; }
    {
      bf16x8 x1 = *(const bf16x8*)(qkv + inbase);
      bf16x8 x2 = *(const bf16x8*)(qkv + inbase + 32);
      bf16x8 o1, o2;
#pragma unroll
      for (int j = 0; j < 8; j++) {
        float a = bf2f(x1[j]), bb = bf2f(x2[j]);
        o1[j] = f2bf((a * c[j] - bb * sn[j]) * QSCALE);
        o2[j] = f2bf((bb * c[j] + a * sn[j]) * QSCALE);
      }
      *(bf16x8*)(Q + outbase + d8) = o1;        // Q not swizzled
      *(bf16x8*)(Q + outbase + d8 + 32) = o2;
    }
    {
      bf16x8 x1 = *(const bf16x8*)(qkv + inbase + 1024);
      bf16x8 x2 = *(const bf16x8*)(qkv + inbase + 1024 + 32);
      bf16x8 o1, o2;
#pragma unroll
      for (int j = 0; j < 8; j++) {
        float a = bf2f(x1[j]), bb = bf2f(x2[j]);
        o1[j] = f2bf(a * c[j] - bb * sn[j]);
        o2[j] = f2bf(bb * c[j] + a * sn[j]);
      }
      int pc = (t & 3) ^ (s & 7);               // physical chunk for logical chunk t&3
      *(bf16x8*)(K + outbase + pc * 8) = o1;
      *(bf16x8*)(K + outbase + (pc ^ 4) * 8) = o2;   // logical chunk +4
    }
  } else {
    __shared__ short ls[64][72];
    int s0 = (blockIdx.x - SS / 64) * 64;
#pragma unroll
    for (int p = 0; p < 2; p++) {
      int idx = p * 256 + t;
      int r = idx >> 3, c8 = (idx & 7) * 8;
      *(bf16x8*)(&ls[r][c8]) =
          *(const bf16x8*)(qkv + ((size_t)(b * SS + s0 + r)) * 3072 + 2048 + h * 64 + c8);
    }
    __syncthreads();
    int dl = t >> 2, sg = (t & 3) * 16;
    int c = sg >> 5, hi = (sg >> 4) & 1;
    short tmp[16];
#pragma unroll
    for (int j = 0; j < 16; j++) tmp[j] = ls[sg + j][dl];
    size_t rowbase = ((size_t)bh * 64 + dl) * SS + s0;
#pragma unroll
    for (int g = 0; g < 4; g++) {
      short4 o = { tmp[4 * g], tmp[4 * g + 1], tmp[4 * g + 2], tmp[4 * g + 3] };
      int pc = (c * 4 + g) ^ (dl & 7);          // slot-permuted logical chunk c*4+g, swizzled
      *(short4*)(Vt + rowbase + pc * 8 + hi * 4) = o;
    }
  }
}

// ---------------- Flash attention, causal. Split-KV halves + dbuf gload_lds + VALU diet --------
// r10 skeleton (2 LDS buffers, counted vmcnt(4), raw s_barrier, 0 bank conflicts) +
// r11 diet: (a) l via ones-row MFMA (row-sum in the MFMA pipe; deletes 16 VALU adds +
// 2 shuffles per wave-tile); (b) pmax as max3 tree (clang fuses to v_max3_f32).
// r14 lesson: the single-buffer variant of this kernel raced under graph replay; the
// counted-vmcnt + sched_barrier fences here are load-bearing. Do not remove.
__global__ __launch_bounds__(256, 6) void attn_kernel(
    const short* __restrict__ Qp, const short* __restrict__ Kp, const short* __restrict__ Vt,
    short* __restrict__ O, float* __restrict__ Pf) {
  __shared__ __align__(16) short KsF[2][64 * 64];   // [buf][kv][d-chunks swizzled]
  __shared__ __align__(16) short VsF[2][64 * 64];   // [buf][d][kv-slot chunks swizzled]
  int flat = blockIdx.x;
  int wk = (flat & 7) * 128 + (flat >> 3);   // 4 bh per XCD (1024%8==0, bijective)
  int bh = wk >> 5;
  int sub = wk & 31;
  int pr = sub >> 1, half = sub & 1;
  int b = bh >> 4, h = bh & 15;
  int tid = threadIdx.x, lane = tid & 63, w = tid >> 6;
  int row = lane & 15, grp = lane >> 4;
  const int qtH = 31 - pr;
  const int nseg = 1 + half;
  const int ck = (grp ^ (row & 7)) * 8;      // swizzled chunk offset (shorts) for frag reads
  const short one_bf = (short)0x3F80;        // bf16 1.0
  const bf16x8 ones = {one_bf, one_bf, one_bf, one_bf, one_bf, one_bf, one_bf, one_bf};

  const short* Kbase = Kp + (size_t)bh * SS * 64;
  const short* Vbase = Vt + (size_t)bh * 64 * SS;
  const int sr8 = lane >> 3;
  const int sc8 = (lane & 7) * 8;

  auto STAGE = [&](int bufi, int kv0) {      // 4 gload_lds per wave
#pragma unroll
    for (int i = 0; i < 2; i++) {
      int rbase = i * 32 + w * 8;
      async_load16(Kbase + (size_t)(kv0 + rbase + sr8) * 64 + sc8, &KsF[bufi][rbase * 64]);
      async_load16(Vbase + (size_t)(rbase + sr8) * SS + kv0 + sc8, &VsF[bufi][rbase * 64]);
    }
  };

  const int kts0 = half ? 16 : 0;
  int cur = 0;
  STAGE(0, kts0 * 64);

#pragma unroll 1
  for (int s = 0; s < nseg; s++) {
    const int qt  = (s == 0) ? qtH : pr;
    const int kts = (s == 0) ? kts0 : 0;
    const int kte = (s == 0) ? (half ? qtH : 15) : pr;
    const bool fin = (s == 1);
    const int q0 = qt * 64;
    const int q = q0 + w * 16 + row;
    bf16x8 qf0, qf1;
    {
      size_t qb = ((size_t)bh * SS + q) * 64 + grp * 8;
      qf0 = *(const bf16x8*)(Qp + qb);
      qf1 = *(const bf16x8*)(Qp + qb + 32);
    }
    f32x4 acc[4];
    f32x4 acc2 = (f32x4){0.f, 0.f, 0.f, 0.f};     // l accumulator (ones-row MFMA)
#pragma unroll
    for (int d = 0; d < 4; d++) acc[d] = (f32x4){0.f, 0.f, 0.f, 0.f};
    float m = -1e30f;

#pragma unroll 1
    for (int kt = kts; kt <= kte; kt++) {
      int kv0 = kt * 64;
      bool more = (kt < kte) || (s + 1 < nseg);   // wave-uniform
      if (more) {
        STAGE(cur ^ 1, kt < kte ? kv0 + 64 : 0);
        asm volatile("s_waitcnt vmcnt(4)" ::: "memory");
      } else {
        asm volatile("s_waitcnt vmcnt(0)" ::: "memory");
      }
      __builtin_amdgcn_sched_barrier(0);
      __builtin_amdgcn_s_barrier();
      __builtin_amdgcn_sched_barrier(0);
      const short* Kc = &KsF[cur][0];
      const short* Vc = &VsF[cur][0];

      bool last = (kt == qt);
      float sv[4][4];
      __builtin_amdgcn_s_setprio(1);
#pragma unroll
      for (int n = 0; n < 4; n++) {
        if (last && n > w) {
#pragma unroll
          for (int r = 0; r < 4; r++) sv[n][r] = -1e30f;
          continue;
        }
        f32x4 sf = (f32x4){0.f, 0.f, 0.f, 0.f};
        const short* kr_ = Kc + (n * 16 + row) * 64;
        bf16x8 kf0 = *(const bf16x8*)(kr_ + ck);
        bf16x8 kf1 = *(const bf16x8*)(kr_ + (ck ^ 32));
        sf = __builtin_amdgcn_mfma_f32_16x16x32_bf16(kf0, qf0, sf, 0, 0, 0);
        sf = __builtin_amdgcn_mfma_f32_16x16x32_bf16(kf1, qf1, sf, 0, 0, 0);
#pragma unroll
        for (int r = 0; r < 4; r++) sv[n][r] = sf[r];
      }
      __builtin_amdgcn_s_setprio(0);
      if (last) {
#pragma unroll
        for (int n = 0; n < 4; n++)
#pragma unroll
          for (int r = 0; r < 4; r++) {
            int kv = kv0 + n * 16 + grp * 4 + r;
            if (kv > q) sv[n][r] = -1e30f;
          }
      }
      // pmax: max3-shaped tree over 16 (clang fuses to v_max3_f32), then 2 shuffles
      float t0 = fmaxf(fmaxf(sv[0][0], sv[0][1]), sv[0][2]);
      float t1 = fmaxf(fmaxf(sv[0][3], sv[1][0]), sv[1][1]);
      float t2 = fmaxf(fmaxf(sv[1][2], sv[1][3]), sv[2][0]);
      float t3 = fmaxf(fmaxf(sv[2][1], sv[2][2]), sv[2][3]);
      float t4 = fmaxf(fmaxf(sv[3][0], sv[3][1]), sv[3][2]);
      float pmax = fmaxf(fmaxf(fmaxf(t0, t1), fmaxf(t2, t3)), fmaxf(t4, sv[3][3]));
      pmax = fmaxf(pmax, __shfl_xor(pmax, 16));
      pmax = fmaxf(pmax, __shfl_xor(pmax, 32));
      // T13 defer-rescale (exp2 headroom 2^8)
      if (__any(pmax - m > 8.f)) {
        float mnew = fmaxf(m, pmax);
        float resc = __builtin_amdgcn_exp2f(m - mnew);
        m = mnew;
#pragma unroll
        for (int d = 0; d < 4; d++)
#pragma unroll
          for (int r = 0; r < 4; r++) acc[d][r] *= resc;
#pragma unroll
        for (int r = 0; r < 4; r++) acc2[r] *= resc;
      }
#pragma unroll
      for (int n = 0; n < 4; n++)
#pragma unroll
        for (int r = 0; r < 4; r++)
          sv[n][r] = __builtin_amdgcn_exp2f(sv[n][r] - m);
      // PV + l: O^T = mfma(V^T_frag, P); l row-sum via ones-frag MFMA (same P operand)
      __builtin_amdgcn_s_setprio(1);
#pragma unroll
      for (int c = 0; c < 2; c++) {
        union { unsigned int u[4]; bf16x8 v; } pu;
        pu.u[0] = cvtpk_bf16(sv[2 * c][0], sv[2 * c][1]);
        pu.u[1] = cvtpk_bf16(sv[2 * c][2], sv[2 * c][3]);
        pu.u[2] = cvtpk_bf16(sv[2 * c + 1][0], sv[2 * c + 1][1]);
        pu.u[3] = cvtpk_bf16(sv[2 * c + 1][2], sv[2 * c + 1][3]);
#pragma unroll
        for (int dm = 0; dm < 4; dm++) {
          const short* vr_ = Vc + (dm * 16 + row) * 64;
          bf16x8 vf = *(const bf16x8*)(vr_ + (ck ^ (c * 32)));
          acc[dm] = __builtin_amdgcn_mfma_f32_16x16x32_bf16(vf, pu.v, acc[dm], 0, 0, 0);
        }
        acc2 = __builtin_amdgcn_mfma_f32_16x16x32_bf16(ones, pu.v, acc2, 0, 0, 0);
      }
      __builtin_amdgcn_s_setprio(0);
      __builtin_amdgcn_sched_barrier(0);
      __builtin_amdgcn_s_barrier();
      __builtin_amdgcn_sched_barrier(0);
      cur ^= 1;
    }
    if (fin) {
      float linv = 1.0f / acc2[0];
      size_t ob = ((size_t)(b * SS + q)) * 1024 + h * 64 + grp * 4;
#pragma unroll
      for (int dm = 0; dm < 4; dm++) {
        union { unsigned int u[2]; short4 s4; } ou;
        ou.u[0] = cvtpk_bf16(acc[dm][0] * linv, acc[dm][1] * linv);
        ou.u[1] = cvtpk_bf16(acc[dm][2] * linv, acc[dm][3] * linv);
        *(short4*)(O + ob + dm * 16) = ou.s4;
      }
    } else {
      int slot = (bh * 16 + (qt - 16)) * 2 + half;
      float* P = Pf + (size_t)slot * 64 * 68 + (w * 16 + row) * 68;
#pragma unroll
      for (int dm = 0; dm < 4; dm++) {
        f32x4 a = acc[dm];
        *(float4*)(P + dm * 16 + grp * 4) = *(float4*)&a;
      }
      if (grp == 0) { P[64] = m; P[65] = acc2[0]; }
    }
  }
}

// ---------------- merge the two heavy-half partials ----------------
__global__ __launch_bounds__(64) void merge_kernel(const float* __restrict__ Pf, short* __restrict__ O) {
  int bh = blockIdx.x >> 4, ht = blockIdx.x & 15;
  int b = bh >> 4, h = bh & 15;
  int qt = ht + 16;
  int t = threadIdx.x;                 // q within tile
  const float* p0 = Pf + ((size_t)((bh * 16 + ht) * 2)) * 64 * 68 + t * 68;
  const float* p1 = p0 + 64 * 68;
  float m0 = p0[64], l0 = p0[65], m1 = p1[64], l1 = p1[65];
  float mM = fmaxf(m0, m1);
  float e0 = __builtin_amdgcn_exp2f(m0 - mM);
  float e1 = __builtin_amdgcn_exp2f(m1 - mM);
  float linv = 1.0f / (e0 * l0 + e1 * l1);
  size_t ob = ((size_t)(b * SS + qt * 64 + t)) * 1024 + h * 64;
#pragma unroll
  for (int d8 = 0; d8 < 8; d8++) {
    float4 a0 = *(const float4*)(p0 + d8 * 8);
    float4 a1 = *(const float4*)(p1 + d8 * 8);
    float4 b0 = *(const float4*)(p0 + d8 * 8 + 4);
    float4 b1 = *(const float4*)(p1 + d8 * 8 + 4);
    union { unsigned int u[4]; short4 s4[2]; } ou;
    ou.u[0] = cvtpk_bf16((e0 * a0.x + e1 * a1.x) * linv, (e0 * a0.y + e1 * a1.y) * linv);
    ou.u[1] = cvtpk_bf16((e0 * a0.z + e1 * a1.z) * linv, (e0 * a0.w + e1 * a1.w) * linv);
    ou.u[2] = cvtpk_bf16((e0 * b0.x + e1 * b1.x) * linv, (e0 * b0.y + e1 * b1.y) * linv);
    ou.u[3] = cvtpk_bf16((e0 * b0.z + e1 * b1.z) * linv, (e0 * b0.w + e1 * b1.w) * linv);
    *(short4*)(O + ob + d8 * 8) = ou.s4[0];
    *(short4*)(O + ob + d8 * 8 + 4) = ou.s4[1];
  }
}

extern "C" void kernel_launch(void* const* d_in, const int* in_sizes, int n_in,
                              void* d_out, int out_size, void* d_ws, size_t ws_size,
                              hipStream_t stream) {
  (void)in_sizes; (void)n_in; (void)out_size; (void)ws_size;
  const float* x     = (const float*)d_in[0];
  const float* w_qkv = (const float*)d_in[1];
  const float* w_out = (const float*)d_in[2];
  float* out = (float*)d_out;

  char* ws = (char*)d_ws;
  size_t off = 0;
  auto alloc = [&](size_t bytes) -> void* {
    void* p = ws + off;
    off += (bytes + 255) & ~(size_t)255;
    return p;
  };
  short* xb    = (short*)alloc((size_t)MTOT * DIM * 2);      // dead after GEMM1
  short* wqkvb = (short*)alloc((size_t)3072 * 1024 * 2);
  short* woutb = (short*)alloc((size_t)1024 * 1024 * 2);
  short* qkvb  = (short*)alloc((size_t)MTOT * 3072 * 2);     // dead after ropev -> partial scratch
  short* Qb    = (short*)alloc((size_t)32 * SS * 64 * 2);
  short* Kb    = (short*)alloc((size_t)32 * SS * 64 * 2);
  short* Vtb   = (short*)alloc((size_t)32 * 64 * SS * 2);
  float* ct    = (float*)alloc((size_t)SS * 32 * 4);
  float* st    = (float*)alloc((size_t)SS * 32 * 4);
  short* attnb = xb;         // reuse: xb's last read is GEMM1 (stream-ordered)
  float* Pf    = (float*)qkvb;  // partial scratch: 32*16*2*64*68*4B = 17.8MB <= 25.2MB

  cvt3_kernel<<<2048, 256, 0, stream>>>(x, xb, MTOT * DIM / 4,
                                        w_qkv, wqkvb, 3072 * 1024 / 4,
                                        w_out, woutb, 1024 * 1024 / 4, ct, st);
  gemm_bt<128, false><<<(3072 / 128) * (MTOT / 128), 256, 0, stream>>>(xb, wqkvb, qkvb, MTOT, 3072, 1024);
  ropev_kernel<<<dim3(2 * SS / 64, 32), 256, 0, stream>>>(qkvb, ct, st, Qb, Kb, Vtb);
  attn_kernel<<<1024, 256, 0, stream>>>(Qb, Kb, Vtb, attnb, Pf);
  merge_kernel<<<512, 64, 0, stream>>>(Pf, attnb);
  gemm_bt<64, true><<<(1024 / 64) * (MTOT / 128), 256, 0, stream>>>(attnb, woutb, out, MTOT, 1024, 1024);
}